// Round 1
// baseline (1471.149 us; speedup 1.0000x reference)
//
#include <hip/hip_runtime.h>
#include <math.h>

#define NEG_SLOPE 0.2f

__device__ __forceinline__ unsigned enc_f(float f){
  unsigned u = __float_as_uint(f);
  return (u & 0x80000000u) ? ~u : (u | 0x80000000u);
}
__device__ __forceinline__ float dec_f(unsigned u){
  unsigned b = (u & 0x80000000u) ? (u & 0x7FFFFFFFu) : ~u;
  return __uint_as_float(b);
}

// ---------------- init: cnt=1 (self loop), m/den zero ----------------
extern "C" __global__ void k_init(int N, int* cnt, unsigned* m0, float* den0,
                                  unsigned* m1, float* den1){
  int n = blockIdx.x*blockDim.x + threadIdx.x;
  if(n >= N) return;
  cnt[n] = 1;
  m1[n] = 0u; den1[n] = 0.f;
  #pragma unroll
  for(int h=0; h<8; h++){ m0[n*8+h] = 0u; den0[n*8+h] = 0.f; }
}

// ---------------- CSR build ----------------
extern "C" __global__ void k_count(const int* __restrict__ dsts, int E, int* cnt){
  int e = blockIdx.x*blockDim.x + threadIdx.x;
  if(e >= E) return;
  atomicAdd(&cnt[dsts[e]], 1);
}

extern "C" __global__ void k_scan_partial(const int* __restrict__ cnt, int* part, int N){
  __shared__ int sh[256];
  int t = threadIdx.x, i = blockIdx.x*256 + t;
  sh[t] = (i < N) ? cnt[i] : 0;
  __syncthreads();
  for(int s=128; s>0; s>>=1){
    if(t < s) sh[t] += sh[t+s];
    __syncthreads();
  }
  if(t == 0) part[blockIdx.x] = sh[0];
}

extern "C" __global__ void k_scan_ex(int* part, int NB){
  __shared__ int sh[256];
  int t = threadIdx.x;
  int v = (t < NB) ? part[t] : 0;
  sh[t] = v; __syncthreads();
  for(int s=1; s<256; s<<=1){
    int u = (t >= s) ? sh[t-s] : 0;
    __syncthreads();
    sh[t] += u;
    __syncthreads();
  }
  if(t < NB) part[t] = sh[t] - v;  // exclusive
}

extern "C" __global__ void k_scan_final(const int* __restrict__ cnt, const int* __restrict__ part,
                                        int* offs, int N){
  __shared__ int sh[256];
  int t = threadIdx.x, i = blockIdx.x*256 + t;
  int v = (i < N) ? cnt[i] : 0;
  sh[t] = v; __syncthreads();
  for(int s=1; s<256; s<<=1){
    int u = (t >= s) ? sh[t-s] : 0;
    __syncthreads();
    sh[t] += u;
    __syncthreads();
  }
  int ex = part[blockIdx.x] + sh[t] - v;
  if(i < N) offs[i] = ex;
  if(i == N-1) offs[N] = ex + v;
}

extern "C" __global__ void k_cursor(const int* __restrict__ offs, int* cur, int N){
  int i = blockIdx.x*blockDim.x + threadIdx.x;
  if(i < N) cur[i] = offs[i];
}

extern "C" __global__ void k_scatter(const int* __restrict__ srcs, const int* __restrict__ dsts,
                                     int E, int N, int* cur, int* csr){
  int i = blockIdx.x*blockDim.x + threadIdx.x;
  if(i >= E + N) return;
  int s, d;
  if(i < E){ s = srcs[i]; d = dsts[i]; } else { s = d = i - E; }
  int pos = atomicAdd(&cur[d], 1);
  csr[pos] = s;
}

// ---------------- fp32 tiled GEMM: C[M,Ncols] = A[M,K] @ B[K,Ncols] ----------------
// blockDim (16,16); tile 64x64, 4x4 per thread, KT=16. Ncols % 64 == 0, K % 16 == 0.
__launch_bounds__(256)
extern "C" __global__ void k_gemm(const float* __restrict__ A, int lda,
                                  const float* __restrict__ B, int ldb,
                                  float* __restrict__ C, int ldc,
                                  int M, int K, int Ncols){
  __shared__ float As[16][65];
  __shared__ float Bs[16][65];
  int row0 = blockIdx.y*64, col0 = blockIdx.x*64;
  int tx = threadIdx.x, ty = threadIdx.y;
  int t = ty*16 + tx;
  float acc[4][4] = {};
  for(int k0=0; k0<K; k0+=16){
    #pragma unroll
    for(int l=0; l<4; l++){
      int idx = t + l*256;          // 0..1023
      int i = idx >> 4, kk = idx & 15;
      int r = row0 + i;
      As[kk][i] = (r < M) ? A[(size_t)r*lda + k0 + kk] : 0.f;
    }
    #pragma unroll
    for(int l=0; l<4; l++){
      int idx = t + l*256;
      int kk = idx >> 6, j = idx & 63;
      Bs[kk][j] = B[(size_t)(k0+kk)*ldb + col0 + j];
    }
    __syncthreads();
    #pragma unroll
    for(int kk=0; kk<16; kk++){
      float a[4], b[4];
      #pragma unroll
      for(int q=0; q<4; q++) a[q] = As[kk][ty*4+q];
      #pragma unroll
      for(int p=0; p<4; p++) b[p] = Bs[kk][tx*4+p];
      #pragma unroll
      for(int q=0; q<4; q++)
        #pragma unroll
        for(int p=0; p<4; p++) acc[q][p] = fmaf(a[q], b[p], acc[q][p]);
    }
    __syncthreads();
  }
  #pragma unroll
  for(int q=0; q<4; q++){
    int r = row0 + ty*4 + q;
    if(r < M){
      #pragma unroll
      for(int p=0; p<4; p++) C[(size_t)r*ldc + col0 + tx*4 + p] = acc[q][p];
    }
  }
}

// ---------------- attention logits layer0: als/ald [N,8] ----------------
extern "C" __global__ void k_al0(const float* __restrict__ buf0, const float* __restrict__ as0,
                                 const float* __restrict__ ad0, float* als0, float* ald0, int N){
  int i = blockIdx.x*blockDim.x + threadIdx.x;   // n*8+h
  if(i >= N*8) return;
  int n = i >> 3, h = i & 7;
  const float4* hp = (const float4*)(buf0 + (size_t)n*512 + h*32);
  const float4* ap = (const float4*)(as0 + h*32);
  const float4* dp = (const float4*)(ad0 + h*32);
  float s = 0.f, d = 0.f;
  #pragma unroll
  for(int k=0; k<8; k++){
    float4 hv = hp[k], av = ap[k], dv = dp[k];
    s += hv.x*av.x + hv.y*av.y + hv.z*av.z + hv.w*av.w;
    d += hv.x*dv.x + hv.y*dv.y + hv.z*dv.z + hv.w*dv.w;
  }
  als0[i] = s; ald0[i] = d;
}

// ---------------- edge passes layer0 (8 heads) ----------------
extern "C" __global__ void k_emax0(const int* __restrict__ srcs, const int* __restrict__ dsts,
                                   int E, int N, const float* __restrict__ als0,
                                   const float* __restrict__ ald0, unsigned* m0){
  int e = blockIdx.x*blockDim.x + threadIdx.x;
  if(e >= E + N) return;
  int s, d;
  if(e < E){ s = srcs[e]; d = dsts[e]; } else { s = d = e - E; }
  #pragma unroll
  for(int h=0; h<8; h++){
    float v = als0[s*8+h] + ald0[d*8+h];
    v = v > 0.f ? v : NEG_SLOPE*v;
    atomicMax(&m0[d*8+h], enc_f(v));
  }
}

extern "C" __global__ void k_esum0(const int* __restrict__ srcs, const int* __restrict__ dsts,
                                   int E, int N, const float* __restrict__ als0,
                                   const float* __restrict__ ald0,
                                   const unsigned* __restrict__ m0, float* den0){
  int e = blockIdx.x*blockDim.x + threadIdx.x;
  if(e >= E + N) return;
  int s, d;
  if(e < E){ s = srcs[e]; d = dsts[e]; } else { s = d = e - E; }
  #pragma unroll
  for(int h=0; h<8; h++){
    float v = als0[s*8+h] + ald0[d*8+h];
    v = v > 0.f ? v : NEG_SLOPE*v;
    atomicAdd(&den0[d*8+h], expf(v - dec_f(m0[d*8+h])));
  }
}

// ---------------- gather layer0 + bias + residual + ELU -> h1 (into buf0+256) ----------------
extern "C" __global__ void k_gather0(float* __restrict__ buf0,
                                     const float* __restrict__ als0, const float* __restrict__ ald0,
                                     const unsigned* __restrict__ m0, const float* __restrict__ den0,
                                     const int* __restrict__ offs, const int* __restrict__ csr,
                                     const float* __restrict__ b0, const float* __restrict__ br0, int N){
  int n = blockIdx.x*4 + (threadIdx.x >> 6);
  if(n >= N) return;
  int lane = threadIdx.x & 63;
  int h8 = lane & 7;
  float ald_n = ald0[n*8+h8];
  float m_n   = dec_f(m0[n*8+h8]);
  float rden  = 1.f/(den0[n*8+h8] + 1e-16f);
  int beg = offs[n], end = offs[n+1];
  float acc0=0.f, acc1=0.f, acc2=0.f, acc3=0.f;
  int c0=lane, c1=lane+64, c2=lane+128, c3=lane+192;
  int g0=c0>>5, g1=c1>>5, g2=c2>>5, g3=c3>>5;
  for(int k=beg; k<end; k++){
    int s = csr[k];
    float v = als0[s*8+h8] + ald_n;
    v = v > 0.f ? v : NEG_SLOPE*v;
    float a = expf(v - m_n) * rden;
    float a0=__shfl(a,g0), a1=__shfl(a,g1), a2=__shfl(a,g2), a3=__shfl(a,g3);
    const float* hs = buf0 + (size_t)s*512;
    acc0 = fmaf(a0, hs[c0], acc0);
    acc1 = fmaf(a1, hs[c1], acc1);
    acc2 = fmaf(a2, hs[c2], acc2);
    acc3 = fmaf(a3, hs[c3], acc3);
  }
  float* h1 = buf0 + (size_t)n*512 + 256;
  float o0 = acc0 + b0[c0] + h1[c0] + br0[c0];
  float o1 = acc1 + b0[c1] + h1[c1] + br0[c1];
  float o2 = acc2 + b0[c2] + h1[c2] + br0[c2];
  float o3 = acc3 + b0[c3] + h1[c3] + br0[c3];
  h1[c0] = o0 > 0.f ? o0 : expf(o0) - 1.f;
  h1[c1] = o1 > 0.f ? o1 : expf(o1) - 1.f;
  h1[c2] = o2 > 0.f ? o2 : expf(o2) - 1.f;
  h1[c3] = o3 > 0.f ? o3 : expf(o3) - 1.f;
}

// ---------------- layer1 logits ----------------
extern "C" __global__ void k_al1(const float* __restrict__ buf1, const float* __restrict__ as1,
                                 const float* __restrict__ ad1, float* als1, float* ald1, int N){
  int n = blockIdx.x*4 + (threadIdx.x >> 6);
  if(n >= N) return;
  int lane = threadIdx.x & 63;
  float g = buf1[(size_t)n*128 + lane];
  float s = g*as1[lane], d = g*ad1[lane];
  #pragma unroll
  for(int o=32; o>0; o>>=1){ s += __shfl_xor(s,o); d += __shfl_xor(d,o); }
  if(lane == 0){ als1[n] = s; ald1[n] = d; }
}

extern "C" __global__ void k_emax1(const int* __restrict__ srcs, const int* __restrict__ dsts,
                                   int E, int N, const float* __restrict__ als1,
                                   const float* __restrict__ ald1, unsigned* m1){
  int e = blockIdx.x*blockDim.x + threadIdx.x;
  if(e >= E + N) return;
  int s, d;
  if(e < E){ s = srcs[e]; d = dsts[e]; } else { s = d = e - E; }
  float v = als1[s] + ald1[d];
  v = v > 0.f ? v : NEG_SLOPE*v;
  atomicMax(&m1[d], enc_f(v));
}

extern "C" __global__ void k_esum1(const int* __restrict__ srcs, const int* __restrict__ dsts,
                                   int E, int N, const float* __restrict__ als1,
                                   const float* __restrict__ ald1,
                                   const unsigned* __restrict__ m1, float* den1){
  int e = blockIdx.x*blockDim.x + threadIdx.x;
  if(e >= E + N) return;
  int s, d;
  if(e < E){ s = srcs[e]; d = dsts[e]; } else { s = d = e - E; }
  float v = als1[s] + ald1[d];
  v = v > 0.f ? v : NEG_SLOPE*v;
  atomicAdd(&den1[d], expf(v - dec_f(m1[d])));
}

// ---------------- gather layer1 + bias + residual + log_softmax ----------------
extern "C" __global__ void k_gather1(const float* __restrict__ buf1,
                                     const float* __restrict__ als1, const float* __restrict__ ald1,
                                     const unsigned* __restrict__ m1, const float* __restrict__ den1,
                                     const int* __restrict__ offs, const int* __restrict__ csr,
                                     const float* __restrict__ b1, const float* __restrict__ br1,
                                     float* __restrict__ out, int N){
  int n = blockIdx.x*4 + (threadIdx.x >> 6);
  if(n >= N) return;
  int lane = threadIdx.x & 63;
  float ald_n = ald1[n], m_n = dec_f(m1[n]), rden = 1.f/(den1[n] + 1e-16f);
  int beg = offs[n], end = offs[n+1];
  float acc = 0.f;
  for(int k=beg; k<end; k++){
    int s = csr[k];
    float v = als1[s] + ald_n;
    v = v > 0.f ? v : NEG_SLOPE*v;
    float a = expf(v - m_n) * rden;
    acc = fmaf(a, buf1[(size_t)s*128 + lane], acc);
  }
  float val = acc + b1[lane] + buf1[(size_t)n*128 + 64 + lane] + br1[lane];
  float mx = val;
  #pragma unroll
  for(int o=32; o>0; o>>=1) mx = fmaxf(mx, __shfl_xor(mx,o));
  float ex = expf(val - mx), sm = ex;
  #pragma unroll
  for(int o=32; o>0; o>>=1) sm += __shfl_xor(sm,o);
  out[(size_t)n*64 + lane] = val - mx - logf(sm);
}

// ---------------- launch ----------------
extern "C" void kernel_launch(void* const* d_in, const int* in_sizes, int n_in,
                              void* d_out, int out_size, void* d_ws, size_t ws_size,
                              hipStream_t stream){
  const float* x   = (const float*)d_in[0];
  const int*   ei  = (const int*)  d_in[1];
  const float* W0  = (const float*)d_in[2];
  const float* as0 = (const float*)d_in[3];
  const float* ad0 = (const float*)d_in[4];
  const float* b0  = (const float*)d_in[5];
  const float* Wr0 = (const float*)d_in[6];
  const float* br0 = (const float*)d_in[7];
  const float* W1  = (const float*)d_in[8];
  const float* as1 = (const float*)d_in[9];
  const float* ad1 = (const float*)d_in[10];
  const float* b1  = (const float*)d_in[11];
  const float* Wr1 = (const float*)d_in[12];
  const float* br1 = (const float*)d_in[13];
  int N = in_sizes[0] / 256;
  int E = in_sizes[1] / 2;
  const int* srcs = ei;
  const int* dsts = ei + E;
  float* out = (float*)d_out;

  // workspace layout
  float*    buf0 = (float*)d_ws;                     // N*512  (h0 | r0->h1)
  float*    buf1 = buf0 + (size_t)N*512;             // N*128  (g1 | r1)
  float*    als0 = buf1 + (size_t)N*128;             // N*8
  float*    ald0 = als0 + (size_t)N*8;               // N*8
  float*    den0 = ald0 + (size_t)N*8;               // N*8
  unsigned* m0   = (unsigned*)(den0 + (size_t)N*8);  // N*8
  float*    als1 = (float*)(m0 + (size_t)N*8);       // N
  float*    ald1 = als1 + N;                         // N
  float*    den1 = ald1 + N;                         // N
  unsigned* m1   = (unsigned*)(den1 + N);            // N
  int*      cnt  = (int*)(m1 + N);                   // N (also cursor)
  int*      offs = cnt + N;                          // N+1
  int*      part = offs + N + 1;                     // 256
  int*      csr  = part + 256;                       // E+N

  int NB = (N + 255) / 256;
  int ET = E + N;

  hipLaunchKernelGGL(k_init, dim3((N+255)/256), dim3(256), 0, stream, N, cnt, m0, den0, m1, den1);
  hipLaunchKernelGGL(k_count, dim3((E+255)/256), dim3(256), 0, stream, dsts, E, cnt);
  hipLaunchKernelGGL(k_scan_partial, dim3(NB), dim3(256), 0, stream, cnt, part, N);
  hipLaunchKernelGGL(k_scan_ex, dim3(1), dim3(256), 0, stream, part, NB);
  hipLaunchKernelGGL(k_scan_final, dim3(NB), dim3(256), 0, stream, cnt, part, offs, N);
  hipLaunchKernelGGL(k_cursor, dim3((N+255)/256), dim3(256), 0, stream, offs, cnt, N);
  hipLaunchKernelGGL(k_scatter, dim3((ET+255)/256), dim3(256), 0, stream, srcs, dsts, E, N, cnt, csr);

  dim3 gb(16,16);
  // layer0 GEMMs: h0 = x@W0 (cols 0..255), r0 = x@Wr0 (cols 256..511), row stride 512
  hipLaunchKernelGGL(k_gemm, dim3(4,(N+63)/64), gb, 0, stream, x, 256, W0, 256, buf0,     512, N, 256, 256);
  hipLaunchKernelGGL(k_gemm, dim3(4,(N+63)/64), gb, 0, stream, x, 256, Wr0,256, buf0+256, 512, N, 256, 256);
  hipLaunchKernelGGL(k_al0, dim3((N*8+255)/256), dim3(256), 0, stream, buf0, as0, ad0, als0, ald0, N);
  hipLaunchKernelGGL(k_emax0, dim3((ET+255)/256), dim3(256), 0, stream, srcs, dsts, E, N, als0, ald0, m0);
  hipLaunchKernelGGL(k_esum0, dim3((ET+255)/256), dim3(256), 0, stream, srcs, dsts, E, N, als0, ald0, m0, den0);
  hipLaunchKernelGGL(k_gather0, dim3((N+3)/4), dim3(256), 0, stream, buf0, als0, ald0, m0, den0, offs, csr, b0, br0, N);

  // layer1 GEMMs: g1 = h1@W1 (cols 0..63), r1 = h1@Wr1 (cols 64..127), row stride 128
  hipLaunchKernelGGL(k_gemm, dim3(1,(N+63)/64), gb, 0, stream, buf0+256, 512, W1, 64, buf1,    128, N, 256, 64);
  hipLaunchKernelGGL(k_gemm, dim3(1,(N+63)/64), gb, 0, stream, buf0+256, 512, Wr1,64, buf1+64, 128, N, 256, 64);
  hipLaunchKernelGGL(k_al1, dim3((N+3)/4), dim3(256), 0, stream, buf1, as1, ad1, als1, ald1, N);
  hipLaunchKernelGGL(k_emax1, dim3((ET+255)/256), dim3(256), 0, stream, srcs, dsts, E, N, als1, ald1, m1);
  hipLaunchKernelGGL(k_esum1, dim3((ET+255)/256), dim3(256), 0, stream, srcs, dsts, E, N, als1, ald1, m1, den1);
  hipLaunchKernelGGL(k_gather1, dim3((N+3)/4), dim3(256), 0, stream, buf1, als1, ald1, m1, den1, offs, csr, b1, br1, out, N);
}

// Round 2
// 843.764 us; speedup vs baseline: 1.7436x; 1.7436x over previous
//
#include <hip/hip_runtime.h>
#include <math.h>

#define NEG_SLOPE 0.2f

// ---------------- init: cnt=1 (self loop) ----------------
extern "C" __global__ void k_init(int N, int* cnt){
  int n = blockIdx.x*blockDim.x + threadIdx.x;
  if(n < N) cnt[n] = 1;
}

// ---------------- CSR build ----------------
extern "C" __global__ void k_count(const int* __restrict__ dsts, int E, int* cnt){
  int e = blockIdx.x*blockDim.x + threadIdx.x;
  if(e >= E) return;
  atomicAdd(&cnt[dsts[e]], 1);
}

extern "C" __global__ void k_scan_partial(const int* __restrict__ cnt, int* part, int N){
  __shared__ int sh[256];
  int t = threadIdx.x, i = blockIdx.x*256 + t;
  sh[t] = (i < N) ? cnt[i] : 0;
  __syncthreads();
  for(int s=128; s>0; s>>=1){
    if(t < s) sh[t] += sh[t+s];
    __syncthreads();
  }
  if(t == 0) part[blockIdx.x] = sh[0];
}

extern "C" __global__ void k_scan_ex(int* part, int NB){
  __shared__ int sh[256];
  int t = threadIdx.x;
  int v = (t < NB) ? part[t] : 0;
  sh[t] = v; __syncthreads();
  for(int s=1; s<256; s<<=1){
    int u = (t >= s) ? sh[t-s] : 0;
    __syncthreads();
    sh[t] += u;
    __syncthreads();
  }
  if(t < NB) part[t] = sh[t] - v;  // exclusive
}

extern "C" __global__ void k_scan_final(const int* __restrict__ cnt, const int* __restrict__ part,
                                        int* offs, int N){
  __shared__ int sh[256];
  int t = threadIdx.x, i = blockIdx.x*256 + t;
  int v = (i < N) ? cnt[i] : 0;
  sh[t] = v; __syncthreads();
  for(int s=1; s<256; s<<=1){
    int u = (t >= s) ? sh[t-s] : 0;
    __syncthreads();
    sh[t] += u;
    __syncthreads();
  }
  int ex = part[blockIdx.x] + sh[t] - v;
  if(i < N) offs[i] = ex;
  if(i == N-1) offs[N] = ex + v;
}

extern "C" __global__ void k_cursor(const int* __restrict__ offs, int* cur, int N){
  int i = blockIdx.x*blockDim.x + threadIdx.x;
  if(i < N) cur[i] = offs[i];
}

extern "C" __global__ void k_scatter(const int* __restrict__ srcs, const int* __restrict__ dsts,
                                     int E, int N, int* cur, int* csr){
  int i = blockIdx.x*blockDim.x + threadIdx.x;
  if(i >= E + N) return;
  int s, d;
  if(i < E){ s = srcs[i]; d = dsts[i]; } else { s = d = i - E; }
  int pos = atomicAdd(&cur[d], 1);
  csr[pos] = s;
}

// ---------------- fp32 tiled GEMM: C[M,Ncols] = A[M,K] @ B[K,Ncols] ----------------
__launch_bounds__(256)
extern "C" __global__ void k_gemm(const float* __restrict__ A, int lda,
                                  const float* __restrict__ B, int ldb,
                                  float* __restrict__ C, int ldc,
                                  int M, int K, int Ncols){
  __shared__ float As[16][65];
  __shared__ float Bs[16][65];
  int row0 = blockIdx.y*64, col0 = blockIdx.x*64;
  int tx = threadIdx.x, ty = threadIdx.y;
  int t = ty*16 + tx;
  float acc[4][4] = {};
  for(int k0=0; k0<K; k0+=16){
    #pragma unroll
    for(int l=0; l<4; l++){
      int idx = t + l*256;          // 0..1023
      int i = idx >> 4, kk = idx & 15;
      int r = row0 + i;
      As[kk][i] = (r < M) ? A[(size_t)r*lda + k0 + kk] : 0.f;
    }
    #pragma unroll
    for(int l=0; l<4; l++){
      int idx = t + l*256;
      int kk = idx >> 6, j = idx & 63;
      Bs[kk][j] = B[(size_t)(k0+kk)*ldb + col0 + j];
    }
    __syncthreads();
    #pragma unroll
    for(int kk=0; kk<16; kk++){
      float a[4], b[4];
      #pragma unroll
      for(int q=0; q<4; q++) a[q] = As[kk][ty*4+q];
      #pragma unroll
      for(int p=0; p<4; p++) b[p] = Bs[kk][tx*4+p];
      #pragma unroll
      for(int q=0; q<4; q++)
        #pragma unroll
        for(int p=0; p<4; p++) acc[q][p] = fmaf(a[q], b[p], acc[q][p]);
    }
    __syncthreads();
  }
  #pragma unroll
  for(int q=0; q<4; q++){
    int r = row0 + ty*4 + q;
    if(r < M){
      #pragma unroll
      for(int p=0; p<4; p++) C[(size_t)r*ldc + col0 + tx*4 + p] = acc[q][p];
    }
  }
}

// ---------------- attention logits layer0: als/ald [N,8] ----------------
extern "C" __global__ void k_al0(const float* __restrict__ buf0, const float* __restrict__ as0,
                                 const float* __restrict__ ad0, float* als0, float* ald0, int N){
  int i = blockIdx.x*blockDim.x + threadIdx.x;   // n*8+h
  if(i >= N*8) return;
  int n = i >> 3, h = i & 7;
  const float4* hp = (const float4*)(buf0 + (size_t)n*512 + h*32);
  const float4* ap = (const float4*)(as0 + h*32);
  const float4* dp = (const float4*)(ad0 + h*32);
  float s = 0.f, d = 0.f;
  #pragma unroll
  for(int k=0; k<8; k++){
    float4 hv = hp[k], av = ap[k], dv = dp[k];
    s += hv.x*av.x + hv.y*av.y + hv.z*av.z + hv.w*av.w;
    d += hv.x*dv.x + hv.y*dv.y + hv.z*dv.z + hv.w*dv.w;
  }
  als0[i] = s; ald0[i] = d;
}

// ---- gather layer0: fused segmax+segsum+weighted gather + bias + residual + ELU -> h1 ----
extern "C" __global__ void k_gather0(float* __restrict__ buf0,
                                     const float* __restrict__ als0, const float* __restrict__ ald0,
                                     const int* __restrict__ offs, const int* __restrict__ csr,
                                     const float* __restrict__ b0, const float* __restrict__ br0, int N){
  int n = blockIdx.x*4 + (threadIdx.x >> 6);
  if(n >= N) return;
  int lane = threadIdx.x & 63;
  int h8 = lane & 7;
  float ald_n = ald0[n*8+h8];
  int beg = offs[n], end = offs[n+1];

  // pass 1: per-head max over neighbors (redundant across the 8 lanes per head)
  float m = -1e30f;
  for(int k=beg; k<end; k++){
    int s = csr[k];
    float v = als0[s*8+h8] + ald_n;
    v = v > 0.f ? v : NEG_SLOPE*v;
    m = fmaxf(m, v);
  }

  // pass 2: denom + unnormalized weighted accumulate
  int c0=lane, c1=lane+64, c2=lane+128, c3=lane+192;
  int g0=c0>>5, g1=c1>>5, g2=c2>>5, g3=c3>>5;   // source lane holding head c>>5
  float den = 0.f;
  float acc0=0.f, acc1=0.f, acc2=0.f, acc3=0.f;
  for(int k=beg; k<end; k++){
    int s = csr[k];
    float v = als0[s*8+h8] + ald_n;
    v = v > 0.f ? v : NEG_SLOPE*v;
    float a = expf(v - m);
    den += a;
    float a0=__shfl(a,g0), a1=__shfl(a,g1), a2=__shfl(a,g2), a3=__shfl(a,g3);
    const float* hs = buf0 + (size_t)s*512;
    acc0 = fmaf(a0, hs[c0], acc0);
    acc1 = fmaf(a1, hs[c1], acc1);
    acc2 = fmaf(a2, hs[c2], acc2);
    acc3 = fmaf(a3, hs[c3], acc3);
  }
  float rden = 1.f/(den + 1e-16f);
  acc0 *= __shfl(rden,g0);
  acc1 *= __shfl(rden,g1);
  acc2 *= __shfl(rden,g2);
  acc3 *= __shfl(rden,g3);

  float* h1 = buf0 + (size_t)n*512 + 256;
  float o0 = acc0 + b0[c0] + h1[c0] + br0[c0];
  float o1 = acc1 + b0[c1] + h1[c1] + br0[c1];
  float o2 = acc2 + b0[c2] + h1[c2] + br0[c2];
  float o3 = acc3 + b0[c3] + h1[c3] + br0[c3];
  h1[c0] = o0 > 0.f ? o0 : expf(o0) - 1.f;
  h1[c1] = o1 > 0.f ? o1 : expf(o1) - 1.f;
  h1[c2] = o2 > 0.f ? o2 : expf(o2) - 1.f;
  h1[c3] = o3 > 0.f ? o3 : expf(o3) - 1.f;
}

// ---------------- layer1 logits ----------------
extern "C" __global__ void k_al1(const float* __restrict__ buf1, const float* __restrict__ as1,
                                 const float* __restrict__ ad1, float* als1, float* ald1, int N){
  int n = blockIdx.x*4 + (threadIdx.x >> 6);
  if(n >= N) return;
  int lane = threadIdx.x & 63;
  float g = buf1[(size_t)n*128 + lane];
  float s = g*as1[lane], d = g*ad1[lane];
  #pragma unroll
  for(int o=32; o>0; o>>=1){ s += __shfl_xor(s,o); d += __shfl_xor(d,o); }
  if(lane == 0){ als1[n] = s; ald1[n] = d; }
}

// ---- gather layer1: fused segmax+segsum+gather + bias + residual + log_softmax ----
extern "C" __global__ void k_gather1(const float* __restrict__ buf1,
                                     const float* __restrict__ als1, const float* __restrict__ ald1,
                                     const int* __restrict__ offs, const int* __restrict__ csr,
                                     const float* __restrict__ b1, const float* __restrict__ br1,
                                     float* __restrict__ out, int N){
  int n = blockIdx.x*4 + (threadIdx.x >> 6);
  if(n >= N) return;
  int lane = threadIdx.x & 63;
  float ald_n = ald1[n];
  int beg = offs[n], end = offs[n+1];

  float m = -1e30f;
  for(int k=beg; k<end; k++){
    int s = csr[k];
    float v = als1[s] + ald_n;
    v = v > 0.f ? v : NEG_SLOPE*v;
    m = fmaxf(m, v);
  }
  float den = 0.f, acc = 0.f;
  for(int k=beg; k<end; k++){
    int s = csr[k];
    float v = als1[s] + ald_n;
    v = v > 0.f ? v : NEG_SLOPE*v;
    float a = expf(v - m);
    den += a;
    acc = fmaf(a, buf1[(size_t)s*128 + lane], acc);
  }
  acc *= 1.f/(den + 1e-16f);

  float val = acc + b1[lane] + buf1[(size_t)n*128 + 64 + lane] + br1[lane];
  float mx = val;
  #pragma unroll
  for(int o=32; o>0; o>>=1) mx = fmaxf(mx, __shfl_xor(mx,o));
  float ex = expf(val - mx), sm = ex;
  #pragma unroll
  for(int o=32; o>0; o>>=1) sm += __shfl_xor(sm,o);
  out[(size_t)n*64 + lane] = val - mx - logf(sm);
}

// ---------------- launch ----------------
extern "C" void kernel_launch(void* const* d_in, const int* in_sizes, int n_in,
                              void* d_out, int out_size, void* d_ws, size_t ws_size,
                              hipStream_t stream){
  const float* x   = (const float*)d_in[0];
  const int*   ei  = (const int*)  d_in[1];
  const float* W0  = (const float*)d_in[2];
  const float* as0 = (const float*)d_in[3];
  const float* ad0 = (const float*)d_in[4];
  const float* b0  = (const float*)d_in[5];
  const float* Wr0 = (const float*)d_in[6];
  const float* br0 = (const float*)d_in[7];
  const float* W1  = (const float*)d_in[8];
  const float* as1 = (const float*)d_in[9];
  const float* ad1 = (const float*)d_in[10];
  const float* b1  = (const float*)d_in[11];
  const float* Wr1 = (const float*)d_in[12];
  const float* br1 = (const float*)d_in[13];
  int N = in_sizes[0] / 256;
  int E = in_sizes[1] / 2;
  const int* srcs = ei;
  const int* dsts = ei + E;
  float* out = (float*)d_out;

  // workspace layout
  float*    buf0 = (float*)d_ws;                     // N*512  (h0 | r0->h1)
  float*    buf1 = buf0 + (size_t)N*512;             // N*128  (g1 | r1)
  float*    als0 = buf1 + (size_t)N*128;             // N*8
  float*    ald0 = als0 + (size_t)N*8;               // N*8
  float*    als1 = ald0 + (size_t)N*8;               // N
  float*    ald1 = als1 + N;                         // N
  int*      cnt  = (int*)(ald1 + N);                 // N (also cursor)
  int*      offs = cnt + N;                          // N+1
  int*      part = offs + N + 1;                     // 256
  int*      csr  = part + 256;                       // E+N

  int NB = (N + 255) / 256;
  int ET = E + N;

  hipLaunchKernelGGL(k_init, dim3((N+255)/256), dim3(256), 0, stream, N, cnt);
  hipLaunchKernelGGL(k_count, dim3((E+255)/256), dim3(256), 0, stream, dsts, E, cnt);
  hipLaunchKernelGGL(k_scan_partial, dim3(NB), dim3(256), 0, stream, cnt, part, N);
  hipLaunchKernelGGL(k_scan_ex, dim3(1), dim3(256), 0, stream, part, NB);
  hipLaunchKernelGGL(k_scan_final, dim3(NB), dim3(256), 0, stream, cnt, part, offs, N);
  hipLaunchKernelGGL(k_cursor, dim3((N+255)/256), dim3(256), 0, stream, offs, cnt, N);
  hipLaunchKernelGGL(k_scatter, dim3((ET+255)/256), dim3(256), 0, stream, srcs, dsts, E, N, cnt, csr);

  dim3 gb(16,16);
  // layer0 GEMMs: h0 = x@W0 (cols 0..255), r0 = x@Wr0 (cols 256..511), row stride 512
  hipLaunchKernelGGL(k_gemm, dim3(4,(N+63)/64), gb, 0, stream, x, 256, W0, 256, buf0,     512, N, 256, 256);
  hipLaunchKernelGGL(k_gemm, dim3(4,(N+63)/64), gb, 0, stream, x, 256, Wr0,256, buf0+256, 512, N, 256, 256);
  hipLaunchKernelGGL(k_al0, dim3((N*8+255)/256), dim3(256), 0, stream, buf0, as0, ad0, als0, ald0, N);
  hipLaunchKernelGGL(k_gather0, dim3((N+3)/4), dim3(256), 0, stream, buf0, als0, ald0, offs, csr, b0, br0, N);

  // layer1 GEMMs: g1 = h1@W1 (cols 0..63), r1 = h1@Wr1 (cols 64..127), row stride 128
  hipLaunchKernelGGL(k_gemm, dim3(1,(N+63)/64), gb, 0, stream, buf0+256, 512, W1, 64, buf1,    128, N, 256, 64);
  hipLaunchKernelGGL(k_gemm, dim3(1,(N+63)/64), gb, 0, stream, buf0+256, 512, Wr1,64, buf1+64, 128, N, 256, 64);
  hipLaunchKernelGGL(k_al1, dim3((N+3)/4), dim3(256), 0, stream, buf1, as1, ad1, als1, ald1, N);
  hipLaunchKernelGGL(k_gather1, dim3((N+3)/4), dim3(256), 0, stream, buf1, als1, ald1, offs, csr, b1, br1, out, N);
}

// Round 3
// 470.767 us; speedup vs baseline: 3.1250x; 1.7923x over previous
//
#include <hip/hip_runtime.h>
#include <math.h>

#define NEG_SLOPE 0.2f

typedef __attribute__((ext_vector_type(8))) short bf16x8;
typedef __attribute__((ext_vector_type(4))) float f32x4;
typedef __attribute__((ext_vector_type(8))) unsigned short ushort8;

__device__ __forceinline__ float b2f(unsigned short u){
  return __uint_as_float(((unsigned)u) << 16);
}
__device__ __forceinline__ unsigned short f2b(float f){
  unsigned u = __float_as_uint(f);
  return (unsigned short)((u + 0x7FFFu + ((u >> 16) & 1u)) >> 16);
}

// ---------------- init: cnt=1 (self loop) ----------------
extern "C" __global__ void k_init(int N, int* cnt){
  int n = blockIdx.x*blockDim.x + threadIdx.x;
  if(n < N) cnt[n] = 1;
}

// ---------------- CSR build ----------------
extern "C" __global__ void k_count(const int* __restrict__ dsts, int E, int* cnt){
  int e = blockIdx.x*blockDim.x + threadIdx.x;
  if(e >= E) return;
  atomicAdd(&cnt[dsts[e]], 1);
}

extern "C" __global__ void k_scan_partial(const int* __restrict__ cnt, int* part, int N){
  __shared__ int sh[256];
  int t = threadIdx.x, i = blockIdx.x*256 + t;
  sh[t] = (i < N) ? cnt[i] : 0;
  __syncthreads();
  for(int s=128; s>0; s>>=1){
    if(t < s) sh[t] += sh[t+s];
    __syncthreads();
  }
  if(t == 0) part[blockIdx.x] = sh[0];
}

extern "C" __global__ void k_scan_ex(int* part, int NB){
  __shared__ int sh[256];
  int t = threadIdx.x;
  int v = (t < NB) ? part[t] : 0;
  sh[t] = v; __syncthreads();
  for(int s=1; s<256; s<<=1){
    int u = (t >= s) ? sh[t-s] : 0;
    __syncthreads();
    sh[t] += u;
    __syncthreads();
  }
  if(t < NB) part[t] = sh[t] - v;  // exclusive
}

extern "C" __global__ void k_scan_final(const int* __restrict__ cnt, const int* __restrict__ part,
                                        int* offs, int N){
  __shared__ int sh[256];
  int t = threadIdx.x, i = blockIdx.x*256 + t;
  int v = (i < N) ? cnt[i] : 0;
  sh[t] = v; __syncthreads();
  for(int s=1; s<256; s<<=1){
    int u = (t >= s) ? sh[t-s] : 0;
    __syncthreads();
    sh[t] += u;
    __syncthreads();
  }
  int ex = part[blockIdx.x] + sh[t] - v;
  if(i < N) offs[i] = ex;
  if(i == N-1) offs[N] = ex + v;
}

extern "C" __global__ void k_cursor(const int* __restrict__ offs, int* cur, int N){
  int i = blockIdx.x*blockDim.x + threadIdx.x;
  if(i < N) cur[i] = offs[i];
}

extern "C" __global__ void k_scatter(const int* __restrict__ srcs, const int* __restrict__ dsts,
                                     int E, int N, int* cur, int* csr){
  int i = blockIdx.x*blockDim.x + threadIdx.x;
  if(i >= E + N) return;
  int s, d;
  if(i < E){ s = srcs[i]; d = dsts[i]; } else { s = d = i - E; }
  int pos = atomicAdd(&cur[d], 1);
  csr[pos] = s;
}

// ---------------- fp32 -> bf16 cast (8 elems/thread) ----------------
extern "C" __global__ void k_cast_x(const float* __restrict__ x, unsigned short* __restrict__ xb, int n8){
  int i = blockIdx.x*blockDim.x + threadIdx.x;
  if(i >= n8) return;
  const float4* p = (const float4*)(x + (size_t)i*8);
  float4 v0 = p[0], v1 = p[1];
  ushort8 o;
  o[0]=f2b(v0.x); o[1]=f2b(v0.y); o[2]=f2b(v0.z); o[3]=f2b(v0.w);
  o[4]=f2b(v1.x); o[5]=f2b(v1.y); o[6]=f2b(v1.z); o[7]=f2b(v1.w);
  *(ushort8*)(xb + (size_t)i*8) = o;
}

// ---------------- weight transpose+concat -> WT[n][k] bf16, k=0..255 ----------------
extern "C" __global__ void k_wt(const float* __restrict__ WA, const float* __restrict__ WB,
                                int half, int rows, unsigned short* __restrict__ WT){
  int idx = blockIdx.x*blockDim.x + threadIdx.x;
  if(idx >= rows*256) return;
  int n = idx >> 8, k = idx & 255;
  const float* W = (n < half) ? WA : WB;
  int c = (n < half) ? n : n - half;
  WT[idx] = f2b(W[(size_t)k*half + c]);
}

// ---------------- bf16 MFMA GEMM: C[M][NC] = A[M][256] @ WT[NC][256]^T ----------------
// 128x128 tile, BK=64, 256 threads = 4 waves (2x2), each wave 64x64 (4x4 frags 16x16x32).
// LDS linear, XOR-swizzle via pre-swizzled global source (slot ^= row&7).
__launch_bounds__(256)
extern "C" __global__ void k_mgemm(const unsigned short* __restrict__ A,
                                   const unsigned short* __restrict__ WT,
                                   unsigned short* __restrict__ C, int ldc, int M){
  __shared__ unsigned short As[128*64];
  __shared__ unsigned short Bs[128*64];
  int t = threadIdx.x;
  int lane = t & 63, wid = t >> 6;
  int wr = wid >> 1, wc = wid & 1;
  int row0 = blockIdx.y*128, col0 = blockIdx.x*128;
  f32x4 acc[4][4] = {};

  for(int k0 = 0; k0 < 256; k0 += 64){
    #pragma unroll
    for(int i=0; i<4; i++){
      int t2 = i*256 + t;
      int r = t2 >> 3;
      int dslot = (t2 & 7) ^ (r & 7);
      int gr = row0 + r; if(gr >= M) gr = M - 1;
      const unsigned short* ga = A + (size_t)gr*256 + k0 + dslot*8;
      __builtin_amdgcn_global_load_lds((const __attribute__((address_space(1))) unsigned*)ga,
          (__attribute__((address_space(3))) unsigned*)(As + i*2048 + wid*512), 16, 0, 0);
      const unsigned short* gb = WT + (size_t)(col0 + r)*256 + k0 + dslot*8;
      __builtin_amdgcn_global_load_lds((const __attribute__((address_space(1))) unsigned*)gb,
          (__attribute__((address_space(3))) unsigned*)(Bs + i*2048 + wid*512), 16, 0, 0);
    }
    __syncthreads();
    #pragma unroll
    for(int kc=0; kc<2; kc++){
      bf16x8 a[4], b[4];
      int kb = kc*4 + (lane >> 4);
      #pragma unroll
      for(int f=0; f<4; f++){
        int ar = wr*64 + f*16 + (lane & 15);
        a[f] = *(const bf16x8*)&As[ar*64 + ((kb ^ (ar & 7))*8)];
        int br = wc*64 + f*16 + (lane & 15);
        b[f] = *(const bf16x8*)&Bs[br*64 + ((kb ^ (br & 7))*8)];
      }
      #pragma unroll
      for(int fm=0; fm<4; fm++)
        #pragma unroll
        for(int fn=0; fn<4; fn++)
          acc[fm][fn] = __builtin_amdgcn_mfma_f32_16x16x32_bf16(a[fm], b[fn], acc[fm][fn], 0, 0, 0);
    }
    __syncthreads();
  }

  int rb = row0 + wr*64 + ((lane >> 4) << 2);
  int cb = col0 + wc*64 + (lane & 15);
  #pragma unroll
  for(int fm=0; fm<4; fm++){
    #pragma unroll
    for(int r=0; r<4; r++){
      int row = rb + fm*16 + r;
      if(row < M){
        #pragma unroll
        for(int fn=0; fn<4; fn++)
          C[(size_t)row*ldc + cb + fn*16] = f2b(acc[fm][fn][r]);
      }
    }
  }
}

// ---------------- attention logits layer0 (bf16 h0) ----------------
extern "C" __global__ void k_al0(const unsigned short* __restrict__ buf0b, const float* __restrict__ as0,
                                 const float* __restrict__ ad0, float* als0, float* ald0, int N){
  int i = blockIdx.x*blockDim.x + threadIdx.x;   // n*8+h
  if(i >= N*8) return;
  int n = i >> 3, h = i & 7;
  const uint4* hp = (const uint4*)(buf0b + (size_t)n*512 + h*32);
  const float* av = as0 + h*32;
  const float* dv = ad0 + h*32;
  float s = 0.f, d = 0.f;
  #pragma unroll
  for(int q=0; q<4; q++){
    uint4 u = hp[q];
    unsigned w[4] = {u.x, u.y, u.z, u.w};
    #pragma unroll
    for(int j=0; j<4; j++){
      float lo = __uint_as_float(w[j] << 16);
      float hi = __uint_as_float(w[j] & 0xFFFF0000u);
      int c = q*8 + j*2;
      s += lo*av[c] + hi*av[c+1];
      d += lo*dv[c] + hi*dv[c+1];
    }
  }
  als0[i] = s; ald0[i] = d;
}

// ---- gather layer0: fused segmax+segsum+weighted gather + bias + residual + ELU -> h1b (bf16) ----
extern "C" __global__ void k_gather0(const unsigned short* __restrict__ buf0b,
                                     const float* __restrict__ als0, const float* __restrict__ ald0,
                                     const int* __restrict__ offs, const int* __restrict__ csr,
                                     const float* __restrict__ b0, const float* __restrict__ br0,
                                     unsigned short* __restrict__ h1b, int N){
  int n = blockIdx.x*4 + (threadIdx.x >> 6);
  if(n >= N) return;
  int lane = threadIdx.x & 63;
  int h8 = lane & 7;
  float ald_n = ald0[n*8+h8];
  int beg = offs[n], end = offs[n+1];

  float m = -1e30f;
  for(int k=beg; k<end; k++){
    int s = csr[k];
    float v = als0[s*8+h8] + ald_n;
    v = v > 0.f ? v : NEG_SLOPE*v;
    m = fmaxf(m, v);
  }

  int c0=lane, c1=lane+64, c2=lane+128, c3=lane+192;
  int g0=c0>>5, g1=c1>>5, g2=c2>>5, g3=c3>>5;
  float den = 0.f;
  float acc0=0.f, acc1=0.f, acc2=0.f, acc3=0.f;
  for(int k=beg; k<end; k++){
    int s = csr[k];
    float v = als0[s*8+h8] + ald_n;
    v = v > 0.f ? v : NEG_SLOPE*v;
    float a = expf(v - m);
    den += a;
    float a0=__shfl(a,g0), a1=__shfl(a,g1), a2=__shfl(a,g2), a3=__shfl(a,g3);
    const unsigned short* hs = buf0b + (size_t)s*512;
    acc0 = fmaf(a0, b2f(hs[c0]), acc0);
    acc1 = fmaf(a1, b2f(hs[c1]), acc1);
    acc2 = fmaf(a2, b2f(hs[c2]), acc2);
    acc3 = fmaf(a3, b2f(hs[c3]), acc3);
  }
  float rden = 1.f/(den + 1e-16f);
  acc0 *= __shfl(rden,g0);
  acc1 *= __shfl(rden,g1);
  acc2 *= __shfl(rden,g2);
  acc3 *= __shfl(rden,g3);

  const unsigned short* r0 = buf0b + (size_t)n*512 + 256;
  float o0 = acc0 + b0[c0] + b2f(r0[c0]) + br0[c0];
  float o1 = acc1 + b0[c1] + b2f(r0[c1]) + br0[c1];
  float o2 = acc2 + b0[c2] + b2f(r0[c2]) + br0[c2];
  float o3 = acc3 + b0[c3] + b2f(r0[c3]) + br0[c3];
  unsigned short* hn = h1b + (size_t)n*256;
  hn[c0] = f2b(o0 > 0.f ? o0 : expf(o0) - 1.f);
  hn[c1] = f2b(o1 > 0.f ? o1 : expf(o1) - 1.f);
  hn[c2] = f2b(o2 > 0.f ? o2 : expf(o2) - 1.f);
  hn[c3] = f2b(o3 > 0.f ? o3 : expf(o3) - 1.f);
}

// ---------------- layer1 logits (bf16 g1) ----------------
extern "C" __global__ void k_al1(const unsigned short* __restrict__ buf1b, const float* __restrict__ as1,
                                 const float* __restrict__ ad1, float* als1, float* ald1, int N){
  int n = blockIdx.x*4 + (threadIdx.x >> 6);
  if(n >= N) return;
  int lane = threadIdx.x & 63;
  float g = b2f(buf1b[(size_t)n*128 + lane]);
  float s = g*as1[lane], d = g*ad1[lane];
  #pragma unroll
  for(int o=32; o>0; o>>=1){ s += __shfl_xor(s,o); d += __shfl_xor(d,o); }
  if(lane == 0){ als1[n] = s; ald1[n] = d; }
}

// ---- gather layer1: fused segmax+segsum+gather + bias + residual + log_softmax ----
extern "C" __global__ void k_gather1(const unsigned short* __restrict__ buf1b,
                                     const float* __restrict__ als1, const float* __restrict__ ald1,
                                     const int* __restrict__ offs, const int* __restrict__ csr,
                                     const float* __restrict__ b1, const float* __restrict__ br1,
                                     float* __restrict__ out, int N){
  int n = blockIdx.x*4 + (threadIdx.x >> 6);
  if(n >= N) return;
  int lane = threadIdx.x & 63;
  float ald_n = ald1[n];
  int beg = offs[n], end = offs[n+1];

  float m = -1e30f;
  for(int k=beg; k<end; k++){
    int s = csr[k];
    float v = als1[s] + ald_n;
    v = v > 0.f ? v : NEG_SLOPE*v;
    m = fmaxf(m, v);
  }
  float den = 0.f, acc = 0.f;
  for(int k=beg; k<end; k++){
    int s = csr[k];
    float v = als1[s] + ald_n;
    v = v > 0.f ? v : NEG_SLOPE*v;
    float a = expf(v - m);
    den += a;
    acc = fmaf(a, b2f(buf1b[(size_t)s*128 + lane]), acc);
  }
  acc *= 1.f/(den + 1e-16f);

  float val = acc + b1[lane] + b2f(buf1b[(size_t)n*128 + 64 + lane]) + br1[lane];
  float mx = val;
  #pragma unroll
  for(int o=32; o>0; o>>=1) mx = fmaxf(mx, __shfl_xor(mx,o));
  float ex = expf(val - mx), sm = ex;
  #pragma unroll
  for(int o=32; o>0; o>>=1) sm += __shfl_xor(sm,o);
  out[(size_t)n*64 + lane] = val - mx - logf(sm);
}

// ---------------- launch ----------------
extern "C" void kernel_launch(void* const* d_in, const int* in_sizes, int n_in,
                              void* d_out, int out_size, void* d_ws, size_t ws_size,
                              hipStream_t stream){
  const float* x   = (const float*)d_in[0];
  const int*   ei  = (const int*)  d_in[1];
  const float* W0  = (const float*)d_in[2];
  const float* as0 = (const float*)d_in[3];
  const float* ad0 = (const float*)d_in[4];
  const float* b0  = (const float*)d_in[5];
  const float* Wr0 = (const float*)d_in[6];
  const float* br0 = (const float*)d_in[7];
  const float* W1  = (const float*)d_in[8];
  const float* as1 = (const float*)d_in[9];
  const float* ad1 = (const float*)d_in[10];
  const float* b1  = (const float*)d_in[11];
  const float* Wr1 = (const float*)d_in[12];
  const float* br1 = (const float*)d_in[13];
  int N = in_sizes[0] / 256;
  int E = in_sizes[1] / 2;
  const int* srcs = ei;
  const int* dsts = ei + E;
  float* out = (float*)d_out;

  // workspace layout (bf16 feature buffers)
  unsigned short* buf0b = (unsigned short*)d_ws;        // N*512 bf16 (h0 | r0)
  unsigned short* xb    = buf0b + (size_t)N*512;        // N*256 bf16
  unsigned short* h1b   = xb    + (size_t)N*256;        // N*256 bf16
  unsigned short* buf1b = h1b   + (size_t)N*256;        // N*128 bf16 (g1 | r1)
  unsigned short* WT0   = buf1b + (size_t)N*128;        // 512*256 bf16
  unsigned short* WT1   = WT0   + 512*256;              // 128*256 bf16
  float*    als0 = (float*)(WT1 + 128*256);             // N*8
  float*    ald0 = als0 + (size_t)N*8;                  // N*8
  float*    als1 = ald0 + (size_t)N*8;                  // N
  float*    ald1 = als1 + N;                            // N
  int*      cnt  = (int*)(ald1 + N);                    // N (also cursor)
  int*      offs = cnt + N;                             // N+1
  int*      part = offs + N + 1;                        // 256
  int*      csr  = part + 256;                          // E+N

  int NB = (N + 255) / 256;
  int ET = E + N;

  // CSR build
  hipLaunchKernelGGL(k_init, dim3((N+255)/256), dim3(256), 0, stream, N, cnt);
  hipLaunchKernelGGL(k_count, dim3((E+255)/256), dim3(256), 0, stream, dsts, E, cnt);
  hipLaunchKernelGGL(k_scan_partial, dim3(NB), dim3(256), 0, stream, cnt, part, N);
  hipLaunchKernelGGL(k_scan_ex, dim3(1), dim3(256), 0, stream, part, NB);
  hipLaunchKernelGGL(k_scan_final, dim3(NB), dim3(256), 0, stream, cnt, part, offs, N);
  hipLaunchKernelGGL(k_cursor, dim3((N+255)/256), dim3(256), 0, stream, offs, cnt, N);
  hipLaunchKernelGGL(k_scatter, dim3((ET+255)/256), dim3(256), 0, stream, srcs, dsts, E, N, cnt, csr);

  // casts / weight prep
  int n8 = N*256/8;
  hipLaunchKernelGGL(k_cast_x, dim3((n8+255)/256), dim3(256), 0, stream, x, xb, n8);
  hipLaunchKernelGGL(k_wt, dim3((512*256+255)/256), dim3(256), 0, stream, W0, Wr0, 256, 512, WT0);
  hipLaunchKernelGGL(k_wt, dim3((128*256+255)/256), dim3(256), 0, stream, W1, Wr1, 64, 128, WT1);

  int MB = (N + 127) / 128;
  // layer0: buf0b[N][512] = xb @ [W0|Wr0]
  hipLaunchKernelGGL(k_mgemm, dim3(4, MB), dim3(256), 0, stream, xb, WT0, buf0b, 512, N);
  hipLaunchKernelGGL(k_al0, dim3((N*8+255)/256), dim3(256), 0, stream, buf0b, as0, ad0, als0, ald0, N);
  hipLaunchKernelGGL(k_gather0, dim3((N+3)/4), dim3(256), 0, stream, buf0b, als0, ald0, offs, csr, b0, br0, h1b, N);

  // layer1: buf1b[N][128] = h1b @ [W1|Wr1]
  hipLaunchKernelGGL(k_mgemm, dim3(1, MB), dim3(256), 0, stream, h1b, WT1, buf1b, 128, N);
  hipLaunchKernelGGL(k_al1, dim3((N+3)/4), dim3(256), 0, stream, buf1b, as1, ad1, als1, ald1, N);
  hipLaunchKernelGGL(k_gather1, dim3((N+3)/4), dim3(256), 0, stream, buf1b, als1, ald1, offs, csr, b1, br1, out, N);
}

// Round 4
// 418.694 us; speedup vs baseline: 3.5137x; 1.1244x over previous
//
#include <hip/hip_runtime.h>
#include <math.h>

#define NEG_SLOPE 0.2f

typedef __attribute__((ext_vector_type(8))) short bf16x8;
typedef __attribute__((ext_vector_type(4))) float f32x4;
typedef __attribute__((ext_vector_type(8))) unsigned short ushort8;
typedef __attribute__((ext_vector_type(4))) unsigned short ushort4v;

__device__ __forceinline__ float b2f(unsigned short u){
  return __uint_as_float(((unsigned)u) << 16);
}
__device__ __forceinline__ unsigned short f2b(float f){
  unsigned u = __float_as_uint(f);
  return (unsigned short)((u + 0x7FFFu + ((u >> 16) & 1u)) >> 16);
}

// ---------------- init: cnt=1 (self loop) ----------------
extern "C" __global__ void k_init(int N, int* cnt){
  int n = blockIdx.x*blockDim.x + threadIdx.x;
  if(n < N) cnt[n] = 1;
}

// ---------------- CSR build ----------------
extern "C" __global__ void k_count(const int* __restrict__ dsts, int E, int* cnt){
  int e = blockIdx.x*blockDim.x + threadIdx.x;
  if(e >= E) return;
  atomicAdd(&cnt[dsts[e]], 1);
}

extern "C" __global__ void k_scan_partial(const int* __restrict__ cnt, int* part, int N){
  __shared__ int sh[256];
  int t = threadIdx.x, i = blockIdx.x*256 + t;
  sh[t] = (i < N) ? cnt[i] : 0;
  __syncthreads();
  for(int s=128; s>0; s>>=1){
    if(t < s) sh[t] += sh[t+s];
    __syncthreads();
  }
  if(t == 0) part[blockIdx.x] = sh[0];
}

extern "C" __global__ void k_scan_ex(int* part, int NB){
  __shared__ int sh[256];
  int t = threadIdx.x;
  int v = (t < NB) ? part[t] : 0;
  sh[t] = v; __syncthreads();
  for(int s=1; s<256; s<<=1){
    int u = (t >= s) ? sh[t-s] : 0;
    __syncthreads();
    sh[t] += u;
    __syncthreads();
  }
  if(t < NB) part[t] = sh[t] - v;  // exclusive
}

// also writes the scatter cursor (merged k_cursor)
extern "C" __global__ void k_scan_final(const int* __restrict__ cnt, const int* __restrict__ part,
                                        int* offs, int* cur, int N){
  __shared__ int sh[256];
  int t = threadIdx.x, i = blockIdx.x*256 + t;
  int v = (i < N) ? cnt[i] : 0;
  sh[t] = v; __syncthreads();
  for(int s=1; s<256; s<<=1){
    int u = (t >= s) ? sh[t-s] : 0;
    __syncthreads();
    sh[t] += u;
    __syncthreads();
  }
  int ex = part[blockIdx.x] + sh[t] - v;
  if(i < N){ offs[i] = ex; cur[i] = ex; }
  if(i == N-1) offs[N] = ex + v;
}

extern "C" __global__ void k_scatter(const int* __restrict__ srcs, const int* __restrict__ dsts,
                                     int E, int N, int* cur, int* csr){
  int i = blockIdx.x*blockDim.x + threadIdx.x;
  if(i >= E + N) return;
  int s, d;
  if(i < E){ s = srcs[i]; d = dsts[i]; } else { s = d = i - E; }
  int pos = atomicAdd(&cur[d], 1);
  csr[pos] = s;
}

// ---------------- fp32 -> bf16 cast (8 elems/thread) ----------------
extern "C" __global__ void k_cast_x(const float* __restrict__ x, unsigned short* __restrict__ xb, int n8){
  int i = blockIdx.x*blockDim.x + threadIdx.x;
  if(i >= n8) return;
  const float4* p = (const float4*)(x + (size_t)i*8);
  float4 v0 = p[0], v1 = p[1];
  ushort8 o;
  o[0]=f2b(v0.x); o[1]=f2b(v0.y); o[2]=f2b(v0.z); o[3]=f2b(v0.w);
  o[4]=f2b(v1.x); o[5]=f2b(v1.y); o[6]=f2b(v1.z); o[7]=f2b(v1.w);
  *(ushort8*)(xb + (size_t)i*8) = o;
}

// ---------------- weight transpose+concat -> WT[n][k] bf16, k=0..255 ----------------
extern "C" __global__ void k_wt(const float* __restrict__ WA, const float* __restrict__ WB,
                                int half, int rows, unsigned short* __restrict__ WT){
  int idx = blockIdx.x*blockDim.x + threadIdx.x;
  if(idx >= rows*256) return;
  int n = idx >> 8, k = idx & 255;
  const float* W = (n < half) ? WA : WB;
  int c = (n < half) ? n : n - half;
  WT[idx] = f2b(W[(size_t)k*half + c]);
}

// ---------------- bf16 MFMA GEMM: C[M][NC] = A[M][256] @ WT[NC][256]^T ----------------
__launch_bounds__(256)
extern "C" __global__ void k_mgemm(const unsigned short* __restrict__ A,
                                   const unsigned short* __restrict__ WT,
                                   unsigned short* __restrict__ C, int ldc, int M){
  __shared__ unsigned short As[128*64];
  __shared__ unsigned short Bs[128*64];
  int t = threadIdx.x;
  int lane = t & 63, wid = t >> 6;
  int wr = wid >> 1, wc = wid & 1;
  int row0 = blockIdx.y*128, col0 = blockIdx.x*128;
  f32x4 acc[4][4] = {};

  for(int k0 = 0; k0 < 256; k0 += 64){
    #pragma unroll
    for(int i=0; i<4; i++){
      int t2 = i*256 + t;
      int r = t2 >> 3;
      int dslot = (t2 & 7) ^ (r & 7);
      int gr = row0 + r; if(gr >= M) gr = M - 1;
      const unsigned short* ga = A + (size_t)gr*256 + k0 + dslot*8;
      __builtin_amdgcn_global_load_lds((const __attribute__((address_space(1))) unsigned*)ga,
          (__attribute__((address_space(3))) unsigned*)(As + i*2048 + wid*512), 16, 0, 0);
      const unsigned short* gb = WT + (size_t)(col0 + r)*256 + k0 + dslot*8;
      __builtin_amdgcn_global_load_lds((const __attribute__((address_space(1))) unsigned*)gb,
          (__attribute__((address_space(3))) unsigned*)(Bs + i*2048 + wid*512), 16, 0, 0);
    }
    __syncthreads();
    #pragma unroll
    for(int kc=0; kc<2; kc++){
      bf16x8 a[4], b[4];
      int kb = kc*4 + (lane >> 4);
      #pragma unroll
      for(int f=0; f<4; f++){
        int ar = wr*64 + f*16 + (lane & 15);
        a[f] = *(const bf16x8*)&As[ar*64 + ((kb ^ (ar & 7))*8)];
        int br = wc*64 + f*16 + (lane & 15);
        b[f] = *(const bf16x8*)&Bs[br*64 + ((kb ^ (br & 7))*8)];
      }
      #pragma unroll
      for(int fm=0; fm<4; fm++)
        #pragma unroll
        for(int fn=0; fn<4; fn++)
          acc[fm][fn] = __builtin_amdgcn_mfma_f32_16x16x32_bf16(a[fm], b[fn], acc[fm][fn], 0, 0, 0);
    }
    __syncthreads();
  }

  int rb = row0 + wr*64 + ((lane >> 4) << 2);
  int cb = col0 + wc*64 + (lane & 15);
  #pragma unroll
  for(int fm=0; fm<4; fm++){
    #pragma unroll
    for(int r=0; r<4; r++){
      int row = rb + fm*16 + r;
      if(row < M){
        #pragma unroll
        for(int fn=0; fn<4; fn++)
          C[(size_t)row*ldc + cb + fn*16] = f2b(acc[fm][fn][r]);
      }
    }
  }
}

// ---------------- attention logits layer0 (bf16 h0) ----------------
extern "C" __global__ void k_al0(const unsigned short* __restrict__ buf0b, const float* __restrict__ as0,
                                 const float* __restrict__ ad0, float* als0, float* ald0, int N){
  int i = blockIdx.x*blockDim.x + threadIdx.x;   // n*8+h
  if(i >= N*8) return;
  int n = i >> 3, h = i & 7;
  const uint4* hp = (const uint4*)(buf0b + (size_t)n*512 + h*32);
  const float* av = as0 + h*32;
  const float* dv = ad0 + h*32;
  float s = 0.f, d = 0.f;
  #pragma unroll
  for(int q=0; q<4; q++){
    uint4 u = hp[q];
    unsigned w[4] = {u.x, u.y, u.z, u.w};
    #pragma unroll
    for(int j=0; j<4; j++){
      float lo = __uint_as_float(w[j] << 16);
      float hi = __uint_as_float(w[j] & 0xFFFF0000u);
      int c = q*8 + j*2;
      s += lo*av[c] + hi*av[c+1];
      d += lo*dv[c] + hi*dv[c+1];
    }
  }
  als0[i] = s; ald0[i] = d;
}

// ---- gather layer0: single-pass online softmax, head-aligned channels, no shuffles ----
// lane owns channels c=lane*4..lane*4+3, all in head lane>>3.
extern "C" __global__ void k_gather0(const unsigned short* __restrict__ buf0b,
                                     const float* __restrict__ als0, const float* __restrict__ ald0,
                                     const int* __restrict__ offs, const int* __restrict__ csr,
                                     const float* __restrict__ b0, const float* __restrict__ br0,
                                     unsigned short* __restrict__ h1b, int N){
  int n = blockIdx.x*4 + (threadIdx.x >> 6);
  if(n >= N) return;
  int lane = threadIdx.x & 63;
  int h = lane >> 3;        // head for this lane's channels
  int c = lane*4;           // first channel owned by this lane
  float ald_n = ald0[n*8+h];
  int beg = offs[n], end = offs[n+1];

  float mref = -1e30f;
  float den = 0.f;
  float a0=0.f, a1=0.f, a2=0.f, a3=0.f;
  for(int k=beg; k<end; k++){
    int s = csr[k];
    float v = als0[s*8+h] + ald_n;
    v = v > 0.f ? v : NEG_SLOPE*v;
    if(__any(v - mref > 8.f)){        // defer-max rescale (rare; exact ratio regardless)
      float mn = fmaxf(mref, v);
      float sc = expf(mref - mn);     // ==1 for lanes not updating; ==0 on first edge
      den *= sc; a0 *= sc; a1 *= sc; a2 *= sc; a3 *= sc;
      mref = mn;
    }
    float p = expf(v - mref);
    den += p;
    uint2 u = *(const uint2*)(buf0b + (size_t)s*512 + c);
    a0 = fmaf(p, __uint_as_float(u.x << 16),        a0);
    a1 = fmaf(p, __uint_as_float(u.x & 0xFFFF0000u), a1);
    a2 = fmaf(p, __uint_as_float(u.y << 16),        a2);
    a3 = fmaf(p, __uint_as_float(u.y & 0xFFFF0000u), a3);
  }
  float rden = 1.f/(den + 1e-16f);
  a0 *= rden; a1 *= rden; a2 *= rden; a3 *= rden;

  // bias + residual + ELU, then pack 4 bf16
  float4 bb = *(const float4*)(b0 + c);
  float4 rb = *(const float4*)(br0 + c);
  uint2 ru = *(const uint2*)(buf0b + (size_t)n*512 + 256 + c);
  float o0 = a0 + bb.x + __uint_as_float(ru.x << 16)         + rb.x;
  float o1 = a1 + bb.y + __uint_as_float(ru.x & 0xFFFF0000u) + rb.y;
  float o2 = a2 + bb.z + __uint_as_float(ru.y << 16)         + rb.z;
  float o3 = a3 + bb.w + __uint_as_float(ru.y & 0xFFFF0000u) + rb.w;
  ushort4v o;
  o[0] = f2b(o0 > 0.f ? o0 : expf(o0) - 1.f);
  o[1] = f2b(o1 > 0.f ? o1 : expf(o1) - 1.f);
  o[2] = f2b(o2 > 0.f ? o2 : expf(o2) - 1.f);
  o[3] = f2b(o3 > 0.f ? o3 : expf(o3) - 1.f);
  *(ushort4v*)(h1b + (size_t)n*256 + c) = o;
}

// ---------------- layer1 logits (bf16 g1) ----------------
extern "C" __global__ void k_al1(const unsigned short* __restrict__ buf1b, const float* __restrict__ as1,
                                 const float* __restrict__ ad1, float* als1, float* ald1, int N){
  int n = blockIdx.x*4 + (threadIdx.x >> 6);
  if(n >= N) return;
  int lane = threadIdx.x & 63;
  float g = b2f(buf1b[(size_t)n*128 + lane]);
  float s = g*as1[lane], d = g*ad1[lane];
  #pragma unroll
  for(int o=32; o>0; o>>=1){ s += __shfl_xor(s,o); d += __shfl_xor(d,o); }
  if(lane == 0){ als1[n] = s; ald1[n] = d; }
}

// ---- gather layer1: single-pass online softmax + bias + residual + log_softmax ----
extern "C" __global__ void k_gather1(const unsigned short* __restrict__ buf1b,
                                     const float* __restrict__ als1, const float* __restrict__ ald1,
                                     const int* __restrict__ offs, const int* __restrict__ csr,
                                     const float* __restrict__ b1, const float* __restrict__ br1,
                                     float* __restrict__ out, int N){
  int n = blockIdx.x*4 + (threadIdx.x >> 6);
  if(n >= N) return;
  int lane = threadIdx.x & 63;
  float ald_n = ald1[n];
  int beg = offs[n], end = offs[n+1];

  float mref = -1e30f, den = 0.f, acc = 0.f;
  for(int k=beg; k<end; k++){
    int s = csr[k];
    float v = als1[s] + ald_n;
    v = v > 0.f ? v : NEG_SLOPE*v;
    if(v - mref > 8.f){               // uniform across wave (same v for all lanes)
      float mn = fmaxf(mref, v);
      float sc = expf(mref - mn);
      den *= sc; acc *= sc;
      mref = mn;
    }
    float p = expf(v - mref);
    den += p;
    acc = fmaf(p, b2f(buf1b[(size_t)s*128 + lane]), acc);
  }
  acc *= 1.f/(den + 1e-16f);

  float val = acc + b1[lane] + b2f(buf1b[(size_t)n*128 + 64 + lane]) + br1[lane];
  float mx = val;
  #pragma unroll
  for(int o=32; o>0; o>>=1) mx = fmaxf(mx, __shfl_xor(mx,o));
  float ex = expf(val - mx), sm = ex;
  #pragma unroll
  for(int o=32; o>0; o>>=1) sm += __shfl_xor(sm,o);
  out[(size_t)n*64 + lane] = val - mx - logf(sm);
}

// ---------------- launch ----------------
extern "C" void kernel_launch(void* const* d_in, const int* in_sizes, int n_in,
                              void* d_out, int out_size, void* d_ws, size_t ws_size,
                              hipStream_t stream){
  const float* x   = (const float*)d_in[0];
  const int*   ei  = (const int*)  d_in[1];
  const float* W0  = (const float*)d_in[2];
  const float* as0 = (const float*)d_in[3];
  const float* ad0 = (const float*)d_in[4];
  const float* b0  = (const float*)d_in[5];
  const float* Wr0 = (const float*)d_in[6];
  const float* br0 = (const float*)d_in[7];
  const float* W1  = (const float*)d_in[8];
  const float* as1 = (const float*)d_in[9];
  const float* ad1 = (const float*)d_in[10];
  const float* b1  = (const float*)d_in[11];
  const float* Wr1 = (const float*)d_in[12];
  const float* br1 = (const float*)d_in[13];
  int N = in_sizes[0] / 256;
  int E = in_sizes[1] / 2;
  const int* srcs = ei;
  const int* dsts = ei + E;
  float* out = (float*)d_out;

  // workspace layout (bf16 feature buffers)
  unsigned short* buf0b = (unsigned short*)d_ws;        // N*512 bf16 (h0 | r0)
  unsigned short* xb    = buf0b + (size_t)N*512;        // N*256 bf16
  unsigned short* h1b   = xb    + (size_t)N*256;        // N*256 bf16
  unsigned short* buf1b = h1b   + (size_t)N*256;        // N*128 bf16 (g1 | r1)
  unsigned short* WT0   = buf1b + (size_t)N*128;        // 512*256 bf16
  unsigned short* WT1   = WT0   + 512*256;              // 128*256 bf16
  float*    als0 = (float*)(WT1 + 128*256);             // N*8
  float*    ald0 = als0 + (size_t)N*8;                  // N*8
  float*    als1 = ald0 + (size_t)N*8;                  // N
  float*    ald1 = als1 + N;                            // N
  int*      cnt  = (int*)(ald1 + N);                    // N (also cursor)
  int*      offs = cnt + N;                             // N+1
  int*      part = offs + N + 1;                        // 256
  int*      csr  = part + 256;                          // E+N

  int NB = (N + 255) / 256;
  int ET = E + N;

  // CSR build
  hipLaunchKernelGGL(k_init, dim3((N+255)/256), dim3(256), 0, stream, N, cnt);
  hipLaunchKernelGGL(k_count, dim3((E+255)/256), dim3(256), 0, stream, dsts, E, cnt);
  hipLaunchKernelGGL(k_scan_partial, dim3(NB), dim3(256), 0, stream, cnt, part, N);
  hipLaunchKernelGGL(k_scan_ex, dim3(1), dim3(256), 0, stream, part, NB);
  hipLaunchKernelGGL(k_scan_final, dim3(NB), dim3(256), 0, stream, cnt, part, offs, cnt, N);
  hipLaunchKernelGGL(k_scatter, dim3((ET+255)/256), dim3(256), 0, stream, srcs, dsts, E, N, cnt, csr);

  // casts / weight prep
  int n8 = N*256/8;
  hipLaunchKernelGGL(k_cast_x, dim3((n8+255)/256), dim3(256), 0, stream, x, xb, n8);
  hipLaunchKernelGGL(k_wt, dim3((512*256+255)/256), dim3(256), 0, stream, W0, Wr0, 256, 512, WT0);
  hipLaunchKernelGGL(k_wt, dim3((128*256+255)/256), dim3(256), 0, stream, W1, Wr1, 64, 128, WT1);

  int MB = (N + 127) / 128;
  // layer0: buf0b[N][512] = xb @ [W0|Wr0]
  hipLaunchKernelGGL(k_mgemm, dim3(4, MB), dim3(256), 0, stream, xb, WT0, buf0b, 512, N);
  hipLaunchKernelGGL(k_al0, dim3((N*8+255)/256), dim3(256), 0, stream, buf0b, as0, ad0, als0, ald0, N);
  hipLaunchKernelGGL(k_gather0, dim3((N+3)/4), dim3(256), 0, stream, buf0b, als0, ald0, offs, csr, b0, br0, h1b, N);

  // layer1: buf1b[N][128] = h1b @ [W1|Wr1]
  hipLaunchKernelGGL(k_mgemm, dim3(1, MB), dim3(256), 0, stream, h1b, WT1, buf1b, 128, N);
  hipLaunchKernelGGL(k_al1, dim3((N+3)/4), dim3(256), 0, stream, buf1b, as1, ad1, als1, ald1, N);
  hipLaunchKernelGGL(k_gather1, dim3((N+3)/4), dim3(256), 0, stream, buf1b, als1, ald1, offs, csr, b1, br1, out, N);
}

// Round 5
// 407.110 us; speedup vs baseline: 3.6136x; 1.0285x over previous
//
#include <hip/hip_runtime.h>
#include <math.h>

#define NEG_SLOPE 0.2f

typedef __attribute__((ext_vector_type(8))) short bf16x8;
typedef __attribute__((ext_vector_type(4))) float f32x4;
typedef __attribute__((ext_vector_type(8))) unsigned short ushort8;
typedef __attribute__((ext_vector_type(4))) unsigned short ushort4v;

__device__ __forceinline__ float b2f(unsigned short u){
  return __uint_as_float(((unsigned)u) << 16);
}
__device__ __forceinline__ unsigned short f2b(float f){
  unsigned u = __float_as_uint(f);
  return (unsigned short)((u + 0x7FFFu + ((u >> 16) & 1u)) >> 16);
}

// ---------------- init: cnt=1 (self loop) ----------------
extern "C" __global__ void k_init(int N, int* cnt){
  int n = blockIdx.x*blockDim.x + threadIdx.x;
  if(n < N) cnt[n] = 1;
}

// ---------------- CSR build ----------------
extern "C" __global__ void k_count(const int* __restrict__ dsts, int E, int* cnt){
  int e = blockIdx.x*blockDim.x + threadIdx.x;
  if(e >= E) return;
  atomicAdd(&cnt[dsts[e]], 1);
}

extern "C" __global__ void k_scan_partial(const int* __restrict__ cnt, int* part, int N){
  __shared__ int sh[256];
  int t = threadIdx.x, i = blockIdx.x*256 + t;
  sh[t] = (i < N) ? cnt[i] : 0;
  __syncthreads();
  for(int s=128; s>0; s>>=1){
    if(t < s) sh[t] += sh[t+s];
    __syncthreads();
  }
  if(t == 0) part[blockIdx.x] = sh[0];
}

extern "C" __global__ void k_scan_ex(int* part, int NB){
  __shared__ int sh[256];
  int t = threadIdx.x;
  int v = (t < NB) ? part[t] : 0;
  sh[t] = v; __syncthreads();
  for(int s=1; s<256; s<<=1){
    int u = (t >= s) ? sh[t-s] : 0;
    __syncthreads();
    sh[t] += u;
    __syncthreads();
  }
  if(t < NB) part[t] = sh[t] - v;  // exclusive
}

// also writes the scatter cursor (merged k_cursor)
extern "C" __global__ void k_scan_final(const int* __restrict__ cnt, const int* __restrict__ part,
                                        int* offs, int* cur, int N){
  __shared__ int sh[256];
  int t = threadIdx.x, i = blockIdx.x*256 + t;
  int v = (i < N) ? cnt[i] : 0;
  sh[t] = v; __syncthreads();
  for(int s=1; s<256; s<<=1){
    int u = (t >= s) ? sh[t-s] : 0;
    __syncthreads();
    sh[t] += u;
    __syncthreads();
  }
  int ex = part[blockIdx.x] + sh[t] - v;
  if(i < N){ offs[i] = ex; cur[i] = ex; }
  if(i == N-1) offs[N] = ex + v;
}

extern "C" __global__ void k_scatter(const int* __restrict__ srcs, const int* __restrict__ dsts,
                                     int E, int N, int* cur, int* csr){
  int i = blockIdx.x*blockDim.x + threadIdx.x;
  if(i >= E + N) return;
  int s, d;
  if(i < E){ s = srcs[i]; d = dsts[i]; } else { s = d = i - E; }
  int pos = atomicAdd(&cur[d], 1);
  csr[pos] = s;
}

// ---------------- fp32 -> bf16 cast (8 elems/thread) ----------------
extern "C" __global__ void k_cast_x(const float* __restrict__ x, unsigned short* __restrict__ xb, int n8){
  int i = blockIdx.x*blockDim.x + threadIdx.x;
  if(i >= n8) return;
  const float4* p = (const float4*)(x + (size_t)i*8);
  float4 v0 = p[0], v1 = p[1];
  ushort8 o;
  o[0]=f2b(v0.x); o[1]=f2b(v0.y); o[2]=f2b(v0.z); o[3]=f2b(v0.w);
  o[4]=f2b(v1.x); o[5]=f2b(v1.y); o[6]=f2b(v1.z); o[7]=f2b(v1.w);
  *(ushort8*)(xb + (size_t)i*8) = o;
}

// ---------------- weight transpose+concat -> WT[n][k] bf16, k=0..255 ----------------
extern "C" __global__ void k_wt(const float* __restrict__ WA, const float* __restrict__ WB,
                                int half, int rows, unsigned short* __restrict__ WT){
  int idx = blockIdx.x*blockDim.x + threadIdx.x;
  if(idx >= rows*256) return;
  int n = idx >> 8, k = idx & 255;
  const float* W = (n < half) ? WA : WB;
  int c = (n < half) ? n : n - half;
  WT[idx] = f2b(W[(size_t)k*half + c]);
}

// ---------------- bf16 MFMA GEMM: C[M][NC] = A[M][256] @ WT[NC][256]^T ----------------
__launch_bounds__(256)
extern "C" __global__ void k_mgemm(const unsigned short* __restrict__ A,
                                   const unsigned short* __restrict__ WT,
                                   unsigned short* __restrict__ C, int ldc, int M){
  __shared__ unsigned short As[128*64];
  __shared__ unsigned short Bs[128*64];
  int t = threadIdx.x;
  int lane = t & 63, wid = t >> 6;
  int wr = wid >> 1, wc = wid & 1;
  int row0 = blockIdx.y*128, col0 = blockIdx.x*128;
  f32x4 acc[4][4] = {};

  for(int k0 = 0; k0 < 256; k0 += 64){
    #pragma unroll
    for(int i=0; i<4; i++){
      int t2 = i*256 + t;
      int r = t2 >> 3;
      int dslot = (t2 & 7) ^ (r & 7);
      int gr = row0 + r; if(gr >= M) gr = M - 1;
      const unsigned short* ga = A + (size_t)gr*256 + k0 + dslot*8;
      __builtin_amdgcn_global_load_lds((const __attribute__((address_space(1))) unsigned*)ga,
          (__attribute__((address_space(3))) unsigned*)(As + i*2048 + wid*512), 16, 0, 0);
      const unsigned short* gb = WT + (size_t)(col0 + r)*256 + k0 + dslot*8;
      __builtin_amdgcn_global_load_lds((const __attribute__((address_space(1))) unsigned*)gb,
          (__attribute__((address_space(3))) unsigned*)(Bs + i*2048 + wid*512), 16, 0, 0);
    }
    __syncthreads();
    #pragma unroll
    for(int kc=0; kc<2; kc++){
      bf16x8 a[4], b[4];
      int kb = kc*4 + (lane >> 4);
      #pragma unroll
      for(int f=0; f<4; f++){
        int ar = wr*64 + f*16 + (lane & 15);
        a[f] = *(const bf16x8*)&As[ar*64 + ((kb ^ (ar & 7))*8)];
        int br = wc*64 + f*16 + (lane & 15);
        b[f] = *(const bf16x8*)&Bs[br*64 + ((kb ^ (br & 7))*8)];
      }
      #pragma unroll
      for(int fm=0; fm<4; fm++)
        #pragma unroll
        for(int fn=0; fn<4; fn++)
          acc[fm][fn] = __builtin_amdgcn_mfma_f32_16x16x32_bf16(a[fm], b[fn], acc[fm][fn], 0, 0, 0);
    }
    __syncthreads();
  }

  int rb = row0 + wr*64 + ((lane >> 4) << 2);
  int cb = col0 + wc*64 + (lane & 15);
  #pragma unroll
  for(int fm=0; fm<4; fm++){
    #pragma unroll
    for(int r=0; r<4; r++){
      int row = rb + fm*16 + r;
      if(row < M){
        #pragma unroll
        for(int fn=0; fn<4; fn++)
          C[(size_t)row*ldc + cb + fn*16] = f2b(acc[fm][fn][r]);
      }
    }
  }
}

// ---------------- attention logits layer0 (bf16 h0) ----------------
extern "C" __global__ void k_al0(const unsigned short* __restrict__ buf0b, const float* __restrict__ as0,
                                 const float* __restrict__ ad0, float* als0, float* ald0, int N){
  int i = blockIdx.x*blockDim.x + threadIdx.x;   // n*8+h
  if(i >= N*8) return;
  int n = i >> 3, h = i & 7;
  const uint4* hp = (const uint4*)(buf0b + (size_t)n*512 + h*32);
  const float* av = as0 + h*32;
  const float* dv = ad0 + h*32;
  float s = 0.f, d = 0.f;
  #pragma unroll
  for(int q=0; q<4; q++){
    uint4 u = hp[q];
    unsigned w[4] = {u.x, u.y, u.z, u.w};
    #pragma unroll
    for(int j=0; j<4; j++){
      float lo = __uint_as_float(w[j] << 16);
      float hi = __uint_as_float(w[j] & 0xFFFF0000u);
      int c = q*8 + j*2;
      s += lo*av[c] + hi*av[c+1];
      d += lo*dv[c] + hi*dv[c+1];
    }
  }
  als0[i] = s; ald0[i] = d;
}

// ---- gather layer0: block-per-node, 4-way edge split, depth-2 pipeline, LDS combine ----
// lane owns channels c=lane*4..lane*4+3, all in head lane>>3.
__launch_bounds__(256)
extern "C" __global__ void k_gather0(const unsigned short* __restrict__ buf0b,
                                     const float* __restrict__ als0, const float* __restrict__ ald0,
                                     const int* __restrict__ offs, const int* __restrict__ csr,
                                     const float* __restrict__ b0, const float* __restrict__ br0,
                                     unsigned short* __restrict__ h1b, int N){
  __shared__ float sm[4][64][7];   // [wave][lane][{m,den,a0..a3}] (stride 7: no bank conflicts)
  int n = blockIdx.x;
  int t = threadIdx.x;
  int lane = t & 63, w = t >> 6;
  int h = lane >> 3;
  int c = lane*4;
  float ald_n = ald0[n*8+h];
  int beg = offs[n], end = offs[n+1];

  float mref = -1e30f, den = 0.f;
  float a0=0.f, a1=0.f, a2=0.f, a3=0.f;

  int k = beg + w;
  int s_cur = 0; float al_cur = 0.f; uint2 u_cur; u_cur.x = 0; u_cur.y = 0;
  if(k < end){
    s_cur  = csr[k];
    al_cur = als0[s_cur*8+h];
    u_cur  = *(const uint2*)(buf0b + (size_t)s_cur*512 + c);
  }
  while(k < end){
    int k2 = k + 4;
    int s_nx = 0; float al_nx = 0.f; uint2 u_nx; u_nx.x = 0; u_nx.y = 0;
    if(k2 < end){
      s_nx  = csr[k2];
      al_nx = als0[s_nx*8+h];
      u_nx  = *(const uint2*)(buf0b + (size_t)s_nx*512 + c);
    }
    float v = al_cur + ald_n;
    v = v > 0.f ? v : NEG_SLOPE*v;
    if(__any(v - mref > 8.f)){        // defer-max rescale (rare)
      float mn = fmaxf(mref, v);
      float sc = expf(mref - mn);
      den *= sc; a0 *= sc; a1 *= sc; a2 *= sc; a3 *= sc;
      mref = mn;
    }
    float p = expf(v - mref);
    den += p;
    a0 = fmaf(p, __uint_as_float(u_cur.x << 16),         a0);
    a1 = fmaf(p, __uint_as_float(u_cur.x & 0xFFFF0000u), a1);
    a2 = fmaf(p, __uint_as_float(u_cur.y << 16),         a2);
    a3 = fmaf(p, __uint_as_float(u_cur.y & 0xFFFF0000u), a3);
    s_cur = s_nx; al_cur = al_nx; u_cur = u_nx;
    k = k2;
  }

  sm[w][lane][0] = mref;
  sm[w][lane][1] = den;
  sm[w][lane][2] = a0; sm[w][lane][3] = a1;
  sm[w][lane][4] = a2; sm[w][lane][5] = a3;
  __syncthreads();
  if(w != 0) return;

  float m = sm[0][lane][0];
  #pragma unroll
  for(int j=1; j<4; j++) m = fmaxf(m, sm[j][lane][0]);
  float D=0.f, A0=0.f, A1=0.f, A2=0.f, A3=0.f;
  #pragma unroll
  for(int j=0; j<4; j++){
    float sc = expf(sm[j][lane][0] - m);   // 0 for empty waves
    D  = fmaf(sm[j][lane][1], sc, D);
    A0 = fmaf(sm[j][lane][2], sc, A0);
    A1 = fmaf(sm[j][lane][3], sc, A1);
    A2 = fmaf(sm[j][lane][4], sc, A2);
    A3 = fmaf(sm[j][lane][5], sc, A3);
  }
  float rden = 1.f/(D + 1e-16f);
  A0 *= rden; A1 *= rden; A2 *= rden; A3 *= rden;

  float4 bb = *(const float4*)(b0 + c);
  float4 rb = *(const float4*)(br0 + c);
  uint2 ru = *(const uint2*)(buf0b + (size_t)n*512 + 256 + c);
  float o0 = A0 + bb.x + __uint_as_float(ru.x << 16)         + rb.x;
  float o1 = A1 + bb.y + __uint_as_float(ru.x & 0xFFFF0000u) + rb.y;
  float o2 = A2 + bb.z + __uint_as_float(ru.y << 16)         + rb.z;
  float o3 = A3 + bb.w + __uint_as_float(ru.y & 0xFFFF0000u) + rb.w;
  ushort4v o;
  o[0] = f2b(o0 > 0.f ? o0 : expf(o0) - 1.f);
  o[1] = f2b(o1 > 0.f ? o1 : expf(o1) - 1.f);
  o[2] = f2b(o2 > 0.f ? o2 : expf(o2) - 1.f);
  o[3] = f2b(o3 > 0.f ? o3 : expf(o3) - 1.f);
  *(ushort4v*)(h1b + (size_t)n*256 + c) = o;
}

// ---------------- layer1 logits (bf16 g1) ----------------
extern "C" __global__ void k_al1(const unsigned short* __restrict__ buf1b, const float* __restrict__ as1,
                                 const float* __restrict__ ad1, float* als1, float* ald1, int N){
  int n = blockIdx.x*4 + (threadIdx.x >> 6);
  if(n >= N) return;
  int lane = threadIdx.x & 63;
  float g = b2f(buf1b[(size_t)n*128 + lane]);
  float s = g*as1[lane], d = g*ad1[lane];
  #pragma unroll
  for(int o=32; o>0; o>>=1){ s += __shfl_xor(s,o); d += __shfl_xor(d,o); }
  if(lane == 0){ als1[n] = s; ald1[n] = d; }
}

// ---- gather layer1: block-per-node, 4-way edge split, depth-2 pipeline, LDS combine ----
__launch_bounds__(256)
extern "C" __global__ void k_gather1(const unsigned short* __restrict__ buf1b,
                                     const float* __restrict__ als1, const float* __restrict__ ald1,
                                     const int* __restrict__ offs, const int* __restrict__ csr,
                                     const float* __restrict__ b1, const float* __restrict__ br1,
                                     float* __restrict__ out, int N){
  __shared__ float sm[4][64][5];   // [wave][lane][{m,den,acc}] pad 5
  int n = blockIdx.x;
  int t = threadIdx.x;
  int lane = t & 63, w = t >> 6;
  float ald_n = ald1[n];
  int beg = offs[n], end = offs[n+1];

  float mref = -1e30f, den = 0.f, acc = 0.f;

  int k = beg + w;
  float al_cur = 0.f; unsigned short f_cur = 0;
  if(k < end){
    int s = csr[k];
    al_cur = als1[s];
    f_cur  = buf1b[(size_t)s*128 + lane];
  }
  while(k < end){
    int k2 = k + 4;
    float al_nx = 0.f; unsigned short f_nx = 0;
    if(k2 < end){
      int s = csr[k2];
      al_nx = als1[s];
      f_nx  = buf1b[(size_t)s*128 + lane];
    }
    float v = al_cur + ald_n;
    v = v > 0.f ? v : NEG_SLOPE*v;
    if(v - mref > 8.f){               // wave-uniform
      float mn = fmaxf(mref, v);
      float sc = expf(mref - mn);
      den *= sc; acc *= sc;
      mref = mn;
    }
    float p = expf(v - mref);
    den += p;
    acc = fmaf(p, b2f(f_cur), acc);
    al_cur = al_nx; f_cur = f_nx;
    k = k2;
  }

  sm[w][lane][0] = mref;
  sm[w][lane][1] = den;
  sm[w][lane][2] = acc;
  __syncthreads();
  if(w != 0) return;

  float m = sm[0][lane][0];
  #pragma unroll
  for(int j=1; j<4; j++) m = fmaxf(m, sm[j][lane][0]);
  float D=0.f, A=0.f;
  #pragma unroll
  for(int j=0; j<4; j++){
    float sc = expf(sm[j][lane][0] - m);
    D = fmaf(sm[j][lane][1], sc, D);
    A = fmaf(sm[j][lane][2], sc, A);
  }
  A *= 1.f/(D + 1e-16f);

  float val = A + b1[lane] + b2f(buf1b[(size_t)n*128 + 64 + lane]) + br1[lane];
  float mx = val;
  #pragma unroll
  for(int o=32; o>0; o>>=1) mx = fmaxf(mx, __shfl_xor(mx,o));
  float ex = expf(val - mx), smv = ex;
  #pragma unroll
  for(int o=32; o>0; o>>=1) smv += __shfl_xor(smv,o);
  out[(size_t)n*64 + lane] = val - mx - logf(smv);
}

// ---------------- launch ----------------
extern "C" void kernel_launch(void* const* d_in, const int* in_sizes, int n_in,
                              void* d_out, int out_size, void* d_ws, size_t ws_size,
                              hipStream_t stream){
  const float* x   = (const float*)d_in[0];
  const int*   ei  = (const int*)  d_in[1];
  const float* W0  = (const float*)d_in[2];
  const float* as0 = (const float*)d_in[3];
  const float* ad0 = (const float*)d_in[4];
  const float* b0  = (const float*)d_in[5];
  const float* Wr0 = (const float*)d_in[6];
  const float* br0 = (const float*)d_in[7];
  const float* W1  = (const float*)d_in[8];
  const float* as1 = (const float*)d_in[9];
  const float* ad1 = (const float*)d_in[10];
  const float* b1  = (const float*)d_in[11];
  const float* Wr1 = (const float*)d_in[12];
  const float* br1 = (const float*)d_in[13];
  int N = in_sizes[0] / 256;
  int E = in_sizes[1] / 2;
  const int* srcs = ei;
  const int* dsts = ei + E;
  float* out = (float*)d_out;

  // workspace layout (bf16 feature buffers)
  unsigned short* buf0b = (unsigned short*)d_ws;        // N*512 bf16 (h0 | r0)
  unsigned short* xb    = buf0b + (size_t)N*512;        // N*256 bf16
  unsigned short* h1b   = xb    + (size_t)N*256;        // N*256 bf16
  unsigned short* buf1b = h1b   + (size_t)N*256;        // N*128 bf16 (g1 | r1)
  unsigned short* WT0   = buf1b + (size_t)N*128;        // 512*256 bf16
  unsigned short* WT1   = WT0   + 512*256;              // 128*256 bf16
  float*    als0 = (float*)(WT1 + 128*256);             // N*8
  float*    ald0 = als0 + (size_t)N*8;                  // N*8
  float*    als1 = ald0 + (size_t)N*8;                  // N
  float*    ald1 = als1 + N;                            // N
  int*      cnt  = (int*)(ald1 + N);                    // N (also cursor)
  int*      offs = cnt + N;                             // N+1
  int*      part = offs + N + 1;                        // 256
  int*      csr  = part + 256;                          // E+N

  int NB = (N + 255) / 256;
  int ET = E + N;

  // CSR build
  hipLaunchKernelGGL(k_init, dim3((N+255)/256), dim3(256), 0, stream, N, cnt);
  hipLaunchKernelGGL(k_count, dim3((E+255)/256), dim3(256), 0, stream, dsts, E, cnt);
  hipLaunchKernelGGL(k_scan_partial, dim3(NB), dim3(256), 0, stream, cnt, part, N);
  hipLaunchKernelGGL(k_scan_ex, dim3(1), dim3(256), 0, stream, part, NB);
  hipLaunchKernelGGL(k_scan_final, dim3(NB), dim3(256), 0, stream, cnt, part, offs, cnt, N);
  hipLaunchKernelGGL(k_scatter, dim3((ET+255)/256), dim3(256), 0, stream, srcs, dsts, E, N, cnt, csr);

  // casts / weight prep
  int n8 = N*256/8;
  hipLaunchKernelGGL(k_cast_x, dim3((n8+255)/256), dim3(256), 0, stream, x, xb, n8);
  hipLaunchKernelGGL(k_wt, dim3((512*256+255)/256), dim3(256), 0, stream, W0, Wr0, 256, 512, WT0);
  hipLaunchKernelGGL(k_wt, dim3((128*256+255)/256), dim3(256), 0, stream, W1, Wr1, 64, 128, WT1);

  int MB = (N + 127) / 128;
  // layer0: buf0b[N][512] = xb @ [W0|Wr0]
  hipLaunchKernelGGL(k_mgemm, dim3(4, MB), dim3(256), 0, stream, xb, WT0, buf0b, 512, N);
  hipLaunchKernelGGL(k_al0, dim3((N*8+255)/256), dim3(256), 0, stream, buf0b, as0, ad0, als0, ald0, N);
  hipLaunchKernelGGL(k_gather0, dim3(N), dim3(256), 0, stream, buf0b, als0, ald0, offs, csr, b0, br0, h1b, N);

  // layer1: buf1b[N][128] = h1b @ [W1|Wr1]
  hipLaunchKernelGGL(k_mgemm, dim3(1, MB), dim3(256), 0, stream, h1b, WT1, buf1b, 128, N);
  hipLaunchKernelGGL(k_al1, dim3((N+3)/4), dim3(256), 0, stream, buf1b, as1, ad1, als1, ald1, N);
  hipLaunchKernelGGL(k_gather1, dim3(N), dim3(256), 0, stream, buf1b, als1, ald1, offs, csr, b1, br1, out, N);
}